// Round 9
// baseline (2073.240 us; speedup 1.0000x reference)
//
#include <hip/hip_runtime.h>
#include <hip/hip_bf16.h>

#define T_TOK 4096
#define HID   2048
#define FFN   7168
#define NEXP  8
#define NPAIR (T_TOK * 2)
#define KT1   (HID / 64)   // 32 k-tiles for GEMM1
#define SLAB  16384        // bytes per [n:128][k:64] bf16 slab (= one B half-tile)
#define MT_G  8            // m-tiles of 256 per expert (covers counts <= 2048)

typedef __attribute__((ext_vector_type(8))) short bf16x8;
typedef __attribute__((ext_vector_type(4))) short bf16x4;
typedef __attribute__((ext_vector_type(4))) float f32x4;

union F4 { float4 v; float f[4]; };

__device__ __forceinline__ short f2bfs(float f) {
    unsigned u = __float_as_uint(f);
    return (short)((u + 0x7FFFu + ((u >> 16) & 1u)) >> 16);
}
__device__ __forceinline__ float bf2f(short s) {
    return __uint_as_float(((unsigned)(unsigned short)s) << 16);
}
__device__ __forceinline__ void gl16(const void* g, void* l) {
    __builtin_amdgcn_global_load_lds(
        (const __attribute__((address_space(1))) unsigned int*)g,
        (__attribute__((address_space(3))) unsigned int*)l, 16, 0, 0);
}

// ---------------- Router ----------------
__global__ __launch_bounds__(256) void moe_router(
    const float* __restrict__ x, const float* __restrict__ gw,
    int* __restrict__ counts, int* __restrict__ sel0, int* __restrict__ sel1,
    float* __restrict__ w0o, float* __restrict__ w1o)
{
    int wave = threadIdx.x >> 6, lane = threadIdx.x & 63;
    int t = blockIdx.x * 4 + wave;
    const float* xr = x + (size_t)t * HID;
    float acc[NEXP];
#pragma unroll
    for (int e = 0; e < NEXP; ++e) acc[e] = 0.f;
    for (int i = 0; i < HID / 64; ++i) {
        int k = lane + i * 64;
        float xv = xr[k];
        const float4* g = reinterpret_cast<const float4*>(gw + (size_t)k * NEXP);
        float4 g0 = g[0], g1 = g[1];
        acc[0] += xv * g0.x; acc[1] += xv * g0.y; acc[2] += xv * g0.z; acc[3] += xv * g0.w;
        acc[4] += xv * g1.x; acc[5] += xv * g1.y; acc[6] += xv * g1.z; acc[7] += xv * g1.w;
    }
#pragma unroll
    for (int e = 0; e < NEXP; ++e) {
        float v = acc[e];
#pragma unroll
        for (int s = 32; s > 0; s >>= 1) v += __shfl_xor(v, s);
        acc[e] = v;
    }
    if (lane == 0) {
        float mx = acc[0];
        for (int e = 1; e < NEXP; ++e) mx = fmaxf(mx, acc[e]);
        float p[NEXP];
        for (int e = 0; e < NEXP; ++e) p[e] = __expf(acc[e] - mx);
        int e0 = 0;
        for (int e = 1; e < NEXP; ++e) if (p[e] > p[e0]) e0 = e;
        int e1 = (e0 == 0) ? 1 : 0;
        for (int e = 0; e < NEXP; ++e) if (e != e0 && p[e] > p[e1]) e1 = e;
        float rs = p[e0] + p[e1];
        sel0[t] = e0; sel1[t] = e1;
        w0o[t] = p[e0] / rs; w1o[t] = p[e1] / rs;
        atomicAdd(&counts[e0], 1); atomicAdd(&counts[e1], 1);
    }
}

__global__ void moe_bases(const int* __restrict__ counts, int* __restrict__ bases)
{
    if (threadIdx.x == 0 && blockIdx.x == 0) {
        int b = 0;
        for (int e = 0; e < NEXP; ++e) { bases[e] = b; b += counts[e]; }
    }
}

// ---------------- Deterministic scatter ----------------
__global__ __launch_bounds__(256) void moe_scatter(
    const int* __restrict__ sel0, const int* __restrict__ sel1,
    const float* __restrict__ w0, const float* __restrict__ w1,
    const int* __restrict__ bases, int* __restrict__ pairTok, float* __restrict__ pairW)
{
    int e = blockIdx.x;
    __shared__ int wsum[4];
    __shared__ int runningS;
    int tid = threadIdx.x, wave = tid >> 6, lane = tid & 63;
    if (tid == 0) runningS = bases[e];
    __syncthreads();
    for (int i0 = 0; i0 < T_TOK; i0 += 256) {
        int t = i0 + tid;
        bool f0 = (sel0[t] == e), f1 = (sel1[t] == e);
        bool sel = f0 || f1;
        unsigned long long mm = __ballot(sel);
        if (lane == 0) wsum[wave] = __popcll(mm);
        __syncthreads();
        int woff = 0;
#pragma unroll
        for (int w = 0; w < 4; ++w) if (w < wave) woff += wsum[w];
        int tot = wsum[0] + wsum[1] + wsum[2] + wsum[3];
        int pre = __popcll(mm & ((1ull << lane) - 1ull));
        if (sel) {
            int pos = runningS + woff + pre;
            pairTok[pos] = t;
            pairW[pos] = f0 ? w0[t] : w1[t];
        }
        __syncthreads();
        if (tid == 0) runningS += tot;
        __syncthreads();
    }
}

// ---------------- xperm: gather routed token rows as bf16 ----------------
__global__ __launch_bounds__(256) void moe_xperm(
    const float* __restrict__ x, const int* __restrict__ pairTok,
    short* __restrict__ xperm)
{
    int p = blockIdx.x * 4 + (threadIdx.x >> 6);
    int lane = threadIdx.x & 63;
    const float* s = x + (size_t)pairTok[p] * HID;
    short* d = xperm + (size_t)p * HID;
#pragma unroll
    for (int i = 0; i < HID / 512; ++i) {
        int k = (i * 64 + lane) * 8;
        float4 f0 = *reinterpret_cast<const float4*>(s + k);
        float4 f1 = *reinterpret_cast<const float4*>(s + k + 4);
        union { bf16x8 v; short sh[8]; } u;
        u.sh[0] = f2bfs(f0.x); u.sh[1] = f2bfs(f0.y); u.sh[2] = f2bfs(f0.z); u.sh[3] = f2bfs(f0.w);
        u.sh[4] = f2bfs(f1.x); u.sh[5] = f2bfs(f1.y); u.sh[6] = f2bfs(f1.z); u.sh[7] = f2bfs(f1.w);
        *reinterpret_cast<bf16x8*>(d + k) = u.v;
    }
}

// ---------------- retile: fp32 [K][N] -> bf16 swizzled 16KB slabs [n:128][k:64] ----------------
__global__ __launch_bounds__(256) void moe_retile(
    const float* __restrict__ src, size_t eStride, int rowStride,
    short* __restrict__ dst, int NB, int KT)
{
    int L = blockIdx.x;
    int e = L / (NB * KT);
    int r = L - e * (NB * KT);
    int nb = r / KT, kt = r - nb * KT;
    const float* s0 = src + (size_t)e * eStride + (size_t)(kt * 64) * rowStride + nb * 128;
    __shared__ __align__(16) short S[8192];
    int t = threadIdx.x;
#pragma unroll
    for (int uu = 0; uu < 2; ++uu) {
        int u = t + uu * 256;
        int kq = u >> 5, nq = u & 31;
        const float* p = s0 + (size_t)(kq * 4) * rowStride + nq * 4;
        F4 r0, r1, r2, r3;
        r0.v = *reinterpret_cast<const float4*>(p);
        r1.v = *reinterpret_cast<const float4*>(p + rowStride);
        r2.v = *reinterpret_cast<const float4*>(p + 2 * (size_t)rowStride);
        r3.v = *reinterpret_cast<const float4*>(p + 3 * (size_t)rowStride);
#pragma unroll
        for (int c = 0; c < 4; ++c) {
            int n = nq * 4 + c;
            bf16x4 v = { f2bfs(r0.f[c]), f2bfs(r1.f[c]), f2bfs(r2.f[c]), f2bfs(r3.f[c]) };
            unsigned byte = (unsigned)(n * 128 + (((kq >> 1) ^ (n & 7)) * 16) + (kq & 1) * 8);
            *reinterpret_cast<bf16x4*>(reinterpret_cast<char*>(S) + byte) = v;
        }
    }
    __syncthreads();
    char* d = reinterpret_cast<char*>(dst) + (size_t)L * SLAB;
    const char* sc = reinterpret_cast<const char*>(S);
#pragma unroll
    for (int i = 0; i < 4; ++i)
        *reinterpret_cast<bf16x8*>(d + t * 16 + i * 4096) =
            *reinterpret_cast<const bf16x8*>(sc + t * 16 + i * 4096);
}

// ================== 256x256x64 8-phase GEMM (m201-style) ==================
// 8 waves (512 thr), wave grid 2m x 4n, per-wave 128x64 output.
// LDS: A/B x 2dbuf x 2 half-tiles of 16KB = 128KB. B half = one retile slab.
// Per phase: ds_read frags -> issue 1 half-tile (2 gl16/wave) -> barrier ->
// lgkmcnt(0) -> setprio(1) -> 16 MFMA -> setprio(0) -> barrier.
// vmcnt(4) only at phases 4 & 8 (2 half-tiles outstanding); never drains.
// MODE 0: hA = silu(x@W1).  MODE 1: hbuf = hA * (x@W3).  MODE 2: out += wt*(h@W2).

#define RD_AF(D, HA) do { \
    const char* _A = (const char*)As[D][myAh]; \
    _Pragma("unroll") \
    for (int a = 0; a < 4; ++a) { \
        unsigned _o = afOff[a] + (HA) * 8192; \
        af[a * 2]     = *reinterpret_cast<const bf16x8*>(_A + _o); \
        af[a * 2 + 1] = *reinterpret_cast<const bf16x8*>(_A + (_o ^ 64)); \
    } \
} while (0)

#define RD_BF(D, HJ, DST) do { \
    const char* _B = (const char*)Bs[D][myBh]; \
    _Pragma("unroll") \
    for (int j = 0; j < 2; ++j) { \
        unsigned _o = bfOff[j] + (HJ) * 4096; \
        DST[j * 2]     = *reinterpret_cast<const bf16x8*>(_B + _o); \
        DST[j * 2 + 1] = *reinterpret_cast<const bf16x8*>(_B + (_o ^ 64)); \
    } \
} while (0)

#define DO_MFMA(HA, HJ, BF) do { \
    __builtin_amdgcn_s_setprio(1); \
    _Pragma("unroll") \
    for (int a = 0; a < 4; ++a) \
        _Pragma("unroll") \
        for (int j = 0; j < 2; ++j) { \
            acc[(HA)*4 + a][(HJ)*2 + j] = __builtin_amdgcn_mfma_f32_16x16x32_bf16( \
                af[a*2], BF[j*2], acc[(HA)*4 + a][(HJ)*2 + j], 0, 0, 0); \
            acc[(HA)*4 + a][(HJ)*2 + j] = __builtin_amdgcn_mfma_f32_16x16x32_bf16( \
                af[a*2+1], BF[j*2+1], acc[(HA)*4 + a][(HJ)*2 + j], 0, 0, 0); \
        } \
    __builtin_amdgcn_s_setprio(0); \
} while (0)

#define ISS_A(D, H, T) do { \
    const char* _s0 = aSrc[H][0] + (size_t)(T) * 128; \
    const char* _s1 = aSrc[H][1] + (size_t)(T) * 128; \
    char* _d = (char*)As[D][H] + w * 2048; \
    gl16(_s0, _d); gl16(_s1, _d + 1024); \
} while (0)

#define ISS_B(D, H, T) do { \
    const char* _s = bSrc[H] + (size_t)(T) * SLAB; \
    char* _d = (char*)Bs[D][H] + w * 2048; \
    gl16(_s, _d); gl16(_s + 1024, _d + 1024); \
} while (0)

#define PH_SYNC do { \
    __builtin_amdgcn_s_barrier(); \
    __builtin_amdgcn_sched_barrier(0); \
    asm volatile("s_waitcnt lgkmcnt(0)" ::: "memory"); \
    __builtin_amdgcn_sched_barrier(0); \
} while (0)

#define PH_END do { \
    __builtin_amdgcn_s_barrier(); \
    __builtin_amdgcn_sched_barrier(0); \
} while (0)

#define VMW4 asm volatile("s_waitcnt vmcnt(4)" ::: "memory")
#define VMW0 asm volatile("s_waitcnt vmcnt(0)" ::: "memory")

template<int MODE>
__global__ __launch_bounds__(512, 2) void moe_gemm256(
    const short* __restrict__ Abase, int aStrideElems,
    const short* __restrict__ slabs, int slabsPerE, int KTn, int nbCount,
    const int* __restrict__ counts, const int* __restrict__ bases,
    const short* __restrict__ hA, short* __restrict__ outS,
    const int* __restrict__ pairTok, const float* __restrict__ pairW,
    float* __restrict__ outF, int Fc)
{
    int L = blockIdx.x;
    int e = L & 7;                       // expert <-> XCD binding
    int ii = L >> 3;
    int nb = ii / MT_G, m = ii - nb * MT_G;
    if (nb >= nbCount) return;
    int cnt = counts[e], m0 = m * 256;
    if (m0 >= cnt) return;
    int base = bases[e];
    int rows = cnt - m0; if (rows > 256) rows = 256;

    __shared__ __align__(16) short As[2][2][8192];   // [dbuf][half] 16KB halves
    __shared__ __align__(16) short Bs[2][2][8192];   // 128KB total

    int tid = threadIdx.x, lane = tid & 63, w = tid >> 6;
    int myAh = w >> 2;                   // wave m-index -> its A half
    int myBh = (w & 3) >> 1;             // wave n-index -> its B half

    // A staging sources: half h rows [h*128 + w*16, +16), swizzle key = row%8 = lane>>3
    const char* aSrc[2][2];
#pragma unroll
    for (int h = 0; h < 2; ++h)
#pragma unroll
        for (int gi = 0; gi < 2; ++gi) {
            int row = base + m0 + h * 128 + w * 16 + gi * 8 + (lane >> 3);
            aSrc[h][gi] = reinterpret_cast<const char*>(Abase)
                + (size_t)row * ((size_t)aStrideElems * 2)
                + (unsigned)((((lane & 7) ^ (lane >> 3)) * 16));
        }
    // B staging sources: half h = slab (2*nb + h)
    const char* bSrc[2];
#pragma unroll
    for (int h = 0; h < 2; ++h)
        bSrc[h] = reinterpret_cast<const char*>(slabs)
            + (size_t)((e * slabsPerE + 2 * nb + h) * KTn) * SLAB
            + w * 2048 + lane * 16;

    // fragment read offsets (within a 16KB half; ha:+8192, hj:+4096, ks1: ^64)
    unsigned afOff[4], bfOff[2];
#pragma unroll
    for (int a = 0; a < 4; ++a) {
        int rl = a * 16 + (lane & 15);
        afOff[a] = (unsigned)(rl * 128 + (((lane >> 4) ^ (rl & 7)) * 16));
    }
#pragma unroll
    for (int j = 0; j < 2; ++j) {
        int cl = ((w & 3) & 1) * 64 + j * 16 + (lane & 15);
        bfOff[j] = (unsigned)(cl * 128 + (((lane >> 4) ^ (cl & 7)) * 16));
    }

    f32x4 acc[8][4];
#pragma unroll
    for (int a = 0; a < 8; ++a)
#pragma unroll
        for (int j = 0; j < 4; ++j) acc[a][j] = (f32x4){0.f, 0.f, 0.f, 0.f};

    bf16x8 af[8], bfA[4], bfB[4];

    // ---- prologue: t0 complete + t1 {B0, A0}; wait t0 (outstanding = 4 loads) ----
    ISS_B(0, 0, 0); ISS_B(0, 1, 0); ISS_A(0, 0, 0); ISS_A(0, 1, 0);
    ISS_B(1, 0, 1); ISS_A(1, 0, 1);
    VMW4;
    __builtin_amdgcn_s_barrier();
    __builtin_amdgcn_sched_barrier(0);

    int NI = KTn / 2;
#pragma unroll 1
    for (int i = 0; i < NI - 1; ++i) {
        int t2 = 2 * i + 2, t3 = 2 * i + 3;
        // p1: tile 2i quadrant (0,0)
        RD_AF(0, 0); RD_BF(0, 0, bfA); ISS_B(1, 1, t3 - 2);  // B1(2i+1)
        PH_SYNC; DO_MFMA(0, 0, bfA); PH_END;
        // p2: (0,1)
        RD_BF(0, 1, bfB); ISS_A(1, 1, t3 - 2);               // A1(2i+1)
        PH_SYNC; DO_MFMA(0, 1, bfB); PH_END;
        // p3: (1,0)  [bfA still live]
        RD_AF(0, 1); ISS_B(0, 0, t2);
        PH_SYNC; DO_MFMA(1, 0, bfA); PH_END;
        // p4: (1,1); ensure tile 2i+1 landed
        ISS_A(0, 0, t2);
        VMW4; PH_SYNC; DO_MFMA(1, 1, bfB); PH_END;
        // p5: tile 2i+1 quadrant (0,0)
        RD_AF(1, 0); RD_BF(1, 0, bfA); ISS_B(0, 1, t2);
        PH_SYNC; DO_MFMA(0, 0, bfA); PH_END;
        // p6: (0,1)
        RD_BF(1, 1, bfB); ISS_A(0, 1, t2);
        PH_SYNC; DO_MFMA(0, 1, bfB); PH_END;
        // p7: (1,0)
        RD_AF(1, 1); ISS_B(1, 0, t3);
        PH_SYNC; DO_MFMA(1, 0, bfA); PH_END;
        // p8: (1,1); ensure tile 2i+2 landed
        ISS_A(1, 0, t3);
        VMW4; PH_SYNC; DO_MFMA(1, 1, bfB); PH_END;
    }
    {   // ---- peeled final iteration (tiles KTn-2, KTn-1) ----
        int tl = KTn - 1;
        RD_AF(0, 0); RD_BF(0, 0, bfA); ISS_B(1, 1, tl);
        PH_SYNC; DO_MFMA(0, 0, bfA); PH_END;
        RD_BF(0, 1, bfB); ISS_A(1, 1, tl);
        PH_SYNC; DO_MFMA(0, 1, bfB); PH_END;
        RD_AF(0, 1);
        PH_SYNC; DO_MFMA(1, 0, bfA); PH_END;
        VMW0; PH_SYNC; DO_MFMA(1, 1, bfB); PH_END;
        RD_AF(1, 0); RD_BF(1, 0, bfA);
        PH_SYNC; DO_MFMA(0, 0, bfA); PH_END;
        RD_BF(1, 1, bfB);
        PH_SYNC; DO_MFMA(0, 1, bfB); PH_END;
        RD_AF(1, 1);
        PH_SYNC; DO_MFMA(1, 0, bfA); PH_END;
        PH_SYNC; DO_MFMA(1, 1, bfB); PH_END;
    }

    // ---- epilogue ----
    int hi = lane >> 4, lo = lane & 15;
    int wrow = (w >> 2) * 128, wcol = (w & 3) * 64;
#pragma unroll
    for (int ai = 0; ai < 8; ++ai) {
#pragma unroll
        for (int q = 0; q < 4; ++q) {
            int rowL = wrow + ai * 16 + hi * 4 + q;
            if (rowL < rows) {
                int pr = base + m0 + rowL;
                if constexpr (MODE == 0) {
                    short* dst = outS + (size_t)pr * Fc + nb * 256;
#pragma unroll
                    for (int ji = 0; ji < 4; ++ji) {
                        float z = acc[ai][ji][q];
                        dst[wcol + ji * 16 + lo] = f2bfs(z / (1.f + __expf(-z)));
                    }
                } else if constexpr (MODE == 1) {
                    size_t off = (size_t)pr * Fc + nb * 256;
                    const short* s1 = hA + off;
                    short* dst = outS + off;
#pragma unroll
                    for (int ji = 0; ji < 4; ++ji) {
                        int c = wcol + ji * 16 + lo;
                        dst[c] = f2bfs(bf2f(s1[c]) * acc[ai][ji][q]);
                    }
                } else {
                    int tok = pairTok[pr];
                    float wt = pairW[pr];
                    float* dst = outF + (size_t)tok * HID + nb * 256;
#pragma unroll
                    for (int ji = 0; ji < 4; ++ji)
                        atomicAdd(dst + wcol + ji * 16 + lo, acc[ai][ji][q] * wt);
                }
            }
        }
    }
}

// ---------------- host ----------------
extern "C" void kernel_launch(void* const* d_in, const int* in_sizes, int n_in,
                              void* d_out, int out_size, void* d_ws, size_t ws_size,
                              hipStream_t stream)
{
    const float* x   = (const float*)d_in[0];
    const float* gw  = (const float*)d_in[1];
    const float* w1s = (const float*)d_in[2];
    const float* w3s = (const float*)d_in[3];
    const float* w2s = (const float*)d_in[4];
    float* out = (float*)d_out;
    char* ws = (char*)d_ws;

    int*   counts  = (int*)(ws + 0);
    int*   bases   = (int*)(ws + 128);
    int*   sel0    = (int*)(ws + 1024);
    int*   sel1    = (int*)(ws + 1024 + 4 * T_TOK);
    float* w0f     = (float*)(ws + 1024 + 8 * T_TOK);
    float* w1f     = (float*)(ws + 1024 + 12 * T_TOK);
    int*   pairTok = (int*)(ws + 1024 + 16 * T_TOK);
    float* pairW   = (float*)(ws + 1024 + 16 * T_TOK + 4 * NPAIR);

    // NC must keep FFN chunk a multiple of 256 (28/NC integral)
    const int cands[6] = {1, 2, 4, 7, 14, 28};
    int NC = 28;
    for (int ci = 0; ci < 6; ++ci) {
        int nc = cands[ci];
        int NB128 = 56 / nc, Fcc = FFN / nc, KT2c = Fcc / 64;
        size_t sz13 = (size_t)NEXP * NB128 * KT1 * SLAB;
        size_t sz2  = (size_t)NEXP * 16 * KT2c * SLAB;
        size_t sxp  = (size_t)(NPAIR + 256) * HID * 2;
        size_t shb  = (size_t)(NPAIR + 256) * Fcc * 2;
        if (262144 + 2 * sz13 + sz2 + sxp + 2 * shb <= ws_size) { NC = nc; break; }
    }
    int NB128 = 56 / NC, NB256 = 28 / NC, Fc = FFN / NC, KT2c = Fc / 64;
    size_t sz13 = (size_t)NEXP * NB128 * KT1 * SLAB;
    size_t sz2  = (size_t)NEXP * 16 * KT2c * SLAB;
    size_t sxp  = (size_t)(NPAIR + 256) * HID * 2;
    size_t shb  = (size_t)(NPAIR + 256) * Fc * 2;
    short* w1r   = (short*)(ws + 262144);
    short* w3r   = (short*)(ws + 262144 + sz13);
    short* w2r   = (short*)(ws + 262144 + 2 * sz13);
    short* xperm = (short*)(ws + 262144 + 2 * sz13 + sz2);
    short* hAb   = (short*)(ws + 262144 + 2 * sz13 + sz2 + sxp);
    short* hbuf  = (short*)(ws + 262144 + 2 * sz13 + sz2 + sxp + shb);

    hipMemsetAsync(ws, 0, 1024, stream);
    hipMemsetAsync(d_out, 0, (size_t)out_size * sizeof(float), stream);
    moe_router<<<T_TOK / 4, 256, 0, stream>>>(x, gw, counts, sel0, sel1, w0f, w1f);
    moe_bases<<<1, 64, 0, stream>>>(counts, bases);
    moe_scatter<<<NEXP, 256, 0, stream>>>(sel0, sel1, w0f, w1f, bases, pairTok, pairW);
    moe_xperm<<<NPAIR / 4, 256, 0, stream>>>(x, pairTok, xperm);

    int grid1 = NEXP * NB256 * MT_G;
    int grid2 = NEXP * 8 * MT_G;
    for (int c = 0; c < NC; ++c) {
        moe_retile<<<NEXP * NB128 * KT1, 256, 0, stream>>>(
            w1s + (size_t)c * Fc, (size_t)HID * FFN, FFN, w1r, NB128, KT1);
        moe_retile<<<NEXP * NB128 * KT1, 256, 0, stream>>>(
            w3s + (size_t)c * Fc, (size_t)HID * FFN, FFN, w3r, NB128, KT1);
        moe_retile<<<NEXP * 16 * KT2c, 256, 0, stream>>>(
            w2s + (size_t)(c * Fc) * HID, (size_t)FFN * HID, HID, w2r, 16, KT2c);
        moe_gemm256<0><<<grid1, 512, 0, stream>>>(
            xperm, HID, w1r, NB128, KT1, NB256, counts, bases,
            nullptr, hAb, nullptr, nullptr, nullptr, Fc);
        moe_gemm256<1><<<grid1, 512, 0, stream>>>(
            xperm, HID, w3r, NB128, KT1, NB256, counts, bases,
            hAb, hbuf, nullptr, nullptr, nullptr, Fc);
        moe_gemm256<2><<<grid2, 512, 0, stream>>>(
            hbuf, Fc, w2r, 16, KT2c, 8, counts, bases,
            nullptr, nullptr, pairTok, pairW, out, Fc);
    }
    (void)in_sizes; (void)n_in;
}

// Round 10
// 1899.030 us; speedup vs baseline: 1.0917x; 1.0917x over previous
//
#include <hip/hip_runtime.h>
#include <hip/hip_bf16.h>

#define T_TOK 4096
#define HID   2048
#define FFN   7168
#define NEXP  8
#define NPAIR (T_TOK * 2)
#define KT1   (HID / 64)   // 32 k-tiles for GEMM1
#define SLAB  16384        // bytes per [n:128][k:64] bf16 slab (= one B half-tile)
#define MT_G  8            // m-tiles of 256 per expert (covers counts <= 2048)

typedef __attribute__((ext_vector_type(8))) short bf16x8;
typedef __attribute__((ext_vector_type(4))) short bf16x4;
typedef __attribute__((ext_vector_type(4))) float f32x4;

union F4 { float4 v; float f[4]; };

__device__ __forceinline__ short f2bfs(float f) {
    unsigned u = __float_as_uint(f);
    return (short)((u + 0x7FFFu + ((u >> 16) & 1u)) >> 16);
}
__device__ __forceinline__ float bf2f(short s) {
    return __uint_as_float(((unsigned)(unsigned short)s) << 16);
}
__device__ __forceinline__ void gl16(const void* g, void* l) {
    __builtin_amdgcn_global_load_lds(
        (const __attribute__((address_space(1))) unsigned int*)g,
        (__attribute__((address_space(3))) unsigned int*)l, 16, 0, 0);
}

// ---------------- Router ----------------
__global__ __launch_bounds__(256) void moe_router(
    const float* __restrict__ x, const float* __restrict__ gw,
    int* __restrict__ counts, int* __restrict__ sel0, int* __restrict__ sel1,
    float* __restrict__ w0o, float* __restrict__ w1o)
{
    int wave = threadIdx.x >> 6, lane = threadIdx.x & 63;
    int t = blockIdx.x * 4 + wave;
    const float* xr = x + (size_t)t * HID;
    float acc[NEXP];
#pragma unroll
    for (int e = 0; e < NEXP; ++e) acc[e] = 0.f;
    for (int i = 0; i < HID / 64; ++i) {
        int k = lane + i * 64;
        float xv = xr[k];
        const float4* g = reinterpret_cast<const float4*>(gw + (size_t)k * NEXP);
        float4 g0 = g[0], g1 = g[1];
        acc[0] += xv * g0.x; acc[1] += xv * g0.y; acc[2] += xv * g0.z; acc[3] += xv * g0.w;
        acc[4] += xv * g1.x; acc[5] += xv * g1.y; acc[6] += xv * g1.z; acc[7] += xv * g1.w;
    }
#pragma unroll
    for (int e = 0; e < NEXP; ++e) {
        float v = acc[e];
#pragma unroll
        for (int s = 32; s > 0; s >>= 1) v += __shfl_xor(v, s);
        acc[e] = v;
    }
    if (lane == 0) {
        float mx = acc[0];
        for (int e = 1; e < NEXP; ++e) mx = fmaxf(mx, acc[e]);
        float p[NEXP];
        for (int e = 0; e < NEXP; ++e) p[e] = __expf(acc[e] - mx);
        int e0 = 0;
        for (int e = 1; e < NEXP; ++e) if (p[e] > p[e0]) e0 = e;
        int e1 = (e0 == 0) ? 1 : 0;
        for (int e = 0; e < NEXP; ++e) if (e != e0 && p[e] > p[e1]) e1 = e;
        float rs = p[e0] + p[e1];
        sel0[t] = e0; sel1[t] = e1;
        w0o[t] = p[e0] / rs; w1o[t] = p[e1] / rs;
        atomicAdd(&counts[e0], 1); atomicAdd(&counts[e1], 1);
    }
}

__global__ void moe_bases(const int* __restrict__ counts, int* __restrict__ bases)
{
    if (threadIdx.x == 0 && blockIdx.x == 0) {
        int b = 0;
        for (int e = 0; e < NEXP; ++e) { bases[e] = b; b += counts[e]; }
    }
}

// ---------------- Deterministic scatter ----------------
__global__ __launch_bounds__(256) void moe_scatter(
    const int* __restrict__ sel0, const int* __restrict__ sel1,
    const float* __restrict__ w0, const float* __restrict__ w1,
    const int* __restrict__ bases, int* __restrict__ pairTok, float* __restrict__ pairW)
{
    int e = blockIdx.x;
    __shared__ int wsum[4];
    __shared__ int runningS;
    int tid = threadIdx.x, wave = tid >> 6, lane = tid & 63;
    if (tid == 0) runningS = bases[e];
    __syncthreads();
    for (int i0 = 0; i0 < T_TOK; i0 += 256) {
        int t = i0 + tid;
        bool f0 = (sel0[t] == e), f1 = (sel1[t] == e);
        bool sel = f0 || f1;
        unsigned long long mm = __ballot(sel);
        if (lane == 0) wsum[wave] = __popcll(mm);
        __syncthreads();
        int woff = 0;
#pragma unroll
        for (int w = 0; w < 4; ++w) if (w < wave) woff += wsum[w];
        int tot = wsum[0] + wsum[1] + wsum[2] + wsum[3];
        int pre = __popcll(mm & ((1ull << lane) - 1ull));
        if (sel) {
            int pos = runningS + woff + pre;
            pairTok[pos] = t;
            pairW[pos] = f0 ? w0[t] : w1[t];
        }
        __syncthreads();
        if (tid == 0) runningS += tot;
        __syncthreads();
    }
}

// ---------------- xperm: gather routed token rows as bf16 ----------------
__global__ __launch_bounds__(256) void moe_xperm(
    const float* __restrict__ x, const int* __restrict__ pairTok,
    short* __restrict__ xperm)
{
    int p = blockIdx.x * 4 + (threadIdx.x >> 6);
    int lane = threadIdx.x & 63;
    const float* s = x + (size_t)pairTok[p] * HID;
    short* d = xperm + (size_t)p * HID;
#pragma unroll
    for (int i = 0; i < HID / 512; ++i) {
        int k = (i * 64 + lane) * 8;
        float4 f0 = *reinterpret_cast<const float4*>(s + k);
        float4 f1 = *reinterpret_cast<const float4*>(s + k + 4);
        union { bf16x8 v; short sh[8]; } u;
        u.sh[0] = f2bfs(f0.x); u.sh[1] = f2bfs(f0.y); u.sh[2] = f2bfs(f0.z); u.sh[3] = f2bfs(f0.w);
        u.sh[4] = f2bfs(f1.x); u.sh[5] = f2bfs(f1.y); u.sh[6] = f2bfs(f1.z); u.sh[7] = f2bfs(f1.w);
        *reinterpret_cast<bf16x8*>(d + k) = u.v;
    }
}

// ---------------- retile: fp32 [K][N] -> bf16 swizzled 16KB slabs [n:128][k:64] ----------------
__global__ __launch_bounds__(256) void moe_retile(
    const float* __restrict__ src, size_t eStride, int rowStride,
    short* __restrict__ dst, int NB, int KT)
{
    int L = blockIdx.x;
    int e = L / (NB * KT);
    int r = L - e * (NB * KT);
    int nb = r / KT, kt = r - nb * KT;
    const float* s0 = src + (size_t)e * eStride + (size_t)(kt * 64) * rowStride + nb * 128;
    __shared__ __align__(16) short S[8192];
    int t = threadIdx.x;
#pragma unroll
    for (int uu = 0; uu < 2; ++uu) {
        int u = t + uu * 256;
        int kq = u >> 5, nq = u & 31;
        const float* p = s0 + (size_t)(kq * 4) * rowStride + nq * 4;
        F4 r0, r1, r2, r3;
        r0.v = *reinterpret_cast<const float4*>(p);
        r1.v = *reinterpret_cast<const float4*>(p + rowStride);
        r2.v = *reinterpret_cast<const float4*>(p + 2 * (size_t)rowStride);
        r3.v = *reinterpret_cast<const float4*>(p + 3 * (size_t)rowStride);
#pragma unroll
        for (int c = 0; c < 4; ++c) {
            int n = nq * 4 + c;
            bf16x4 v = { f2bfs(r0.f[c]), f2bfs(r1.f[c]), f2bfs(r2.f[c]), f2bfs(r3.f[c]) };
            unsigned byte = (unsigned)(n * 128 + (((kq >> 1) ^ (n & 7)) * 16) + (kq & 1) * 8);
            *reinterpret_cast<bf16x4*>(reinterpret_cast<char*>(S) + byte) = v;
        }
    }
    __syncthreads();
    char* d = reinterpret_cast<char*>(dst) + (size_t)L * SLAB;
    const char* sc = reinterpret_cast<const char*>(S);
#pragma unroll
    for (int i = 0; i < 4; ++i)
        *reinterpret_cast<bf16x8*>(d + t * 16 + i * 4096) =
            *reinterpret_cast<const bf16x8*>(sc + t * 16 + i * 4096);
}

// ================== 256x256x64 8-phase GEMM, v2 (deep wait-lead) ==================
// 8 waves, wave grid 2m x 4n, per-wave 128x64 output. LDS 128KB (A/B x 2dbuf x 2 half).
// v2 schedule: issues PAIRED at p3 (both B halves of tile t+2), p4 (both A halves),
// p7/p8 (tile t+3); waits vmcnt(8) at p4/p8 -> waited loads are 4-5 phases old
// (R9's v1 waited loads only 2-3 phases old -> L2/L3-latency stall, 422 TF).
// Buffer safety: B[d][h] last ds_read at p2/p6 (lgkm drained + barrier) -> overwrite
// p3/p7; A[d][h] last read at p3/p7 -> overwrite p4/p8.

#define RD_AF(D, HA) do { \
    const char* _A = (const char*)As[D][myAh]; \
    _Pragma("unroll") \
    for (int a = 0; a < 4; ++a) { \
        unsigned _o = afOff[a] + (HA) * 8192; \
        af[a * 2]     = *reinterpret_cast<const bf16x8*>(_A + _o); \
        af[a * 2 + 1] = *reinterpret_cast<const bf16x8*>(_A + (_o ^ 64)); \
    } \
} while (0)

#define RD_BF(D, HJ, DST) do { \
    const char* _B = (const char*)Bs[D][myBh]; \
    _Pragma("unroll") \
    for (int j = 0; j < 2; ++j) { \
        unsigned _o = bfOff[j] + (HJ) * 4096; \
        DST[j * 2]     = *reinterpret_cast<const bf16x8*>(_B + _o); \
        DST[j * 2 + 1] = *reinterpret_cast<const bf16x8*>(_B + (_o ^ 64)); \
    } \
} while (0)

#define DO_MFMA(HA, HJ, BF) do { \
    __builtin_amdgcn_s_setprio(1); \
    _Pragma("unroll") \
    for (int a = 0; a < 4; ++a) \
        _Pragma("unroll") \
        for (int j = 0; j < 2; ++j) { \
            acc[(HA)*4 + a][(HJ)*2 + j] = __builtin_amdgcn_mfma_f32_16x16x32_bf16( \
                af[a*2], BF[j*2], acc[(HA)*4 + a][(HJ)*2 + j], 0, 0, 0); \
            acc[(HA)*4 + a][(HJ)*2 + j] = __builtin_amdgcn_mfma_f32_16x16x32_bf16( \
                af[a*2+1], BF[j*2+1], acc[(HA)*4 + a][(HJ)*2 + j], 0, 0, 0); \
        } \
    __builtin_amdgcn_s_setprio(0); \
} while (0)

#define ISS_A(D, H, T) do { \
    const char* _s0 = aSrc[H][0] + (size_t)(T) * 128; \
    const char* _s1 = aSrc[H][1] + (size_t)(T) * 128; \
    char* _d = (char*)As[D][H] + w * 2048; \
    gl16(_s0, _d); gl16(_s1, _d + 1024); \
} while (0)

#define ISS_B(D, H, T) do { \
    const char* _s = bSrc[H] + (size_t)(T) * SLAB; \
    char* _d = (char*)Bs[D][H] + w * 2048; \
    gl16(_s, _d); gl16(_s + 1024, _d + 1024); \
} while (0)

#define PH_SYNC do { \
    __builtin_amdgcn_s_barrier(); \
    asm volatile("s_waitcnt lgkmcnt(0)" ::: "memory"); \
    __builtin_amdgcn_sched_barrier(0); \
} while (0)

#define PH_END do { \
    __builtin_amdgcn_s_barrier(); \
    __builtin_amdgcn_sched_barrier(0); \
} while (0)

#define VMW8 asm volatile("s_waitcnt vmcnt(8)" ::: "memory")
#define VMW0 asm volatile("s_waitcnt vmcnt(0)" ::: "memory")

template<int MODE>
__global__ __launch_bounds__(512, 2) void moe_gemm256(
    const short* __restrict__ Abase, int aStrideElems,
    const short* __restrict__ slabs, int slabsPerE, int KTn, int nbCount,
    const int* __restrict__ counts, const int* __restrict__ bases,
    const short* __restrict__ hA, short* __restrict__ outS,
    const int* __restrict__ pairTok, const float* __restrict__ pairW,
    float* __restrict__ outF, int Fc)
{
    int L = blockIdx.x;
    int e = L & 7;                       // expert <-> XCD binding
    int ii = L >> 3;
    int nb = ii / MT_G, m = ii - nb * MT_G;
    if (nb >= nbCount) return;
    int cnt = counts[e], m0 = m * 256;
    if (m0 >= cnt) return;
    int base = bases[e];
    int rows = cnt - m0; if (rows > 256) rows = 256;

    __shared__ __align__(16) short As[2][2][8192];   // [dbuf][half] 16KB halves
    __shared__ __align__(16) short Bs[2][2][8192];   // 128KB total

    int tid = threadIdx.x, lane = tid & 63, w = tid >> 6;
    int myAh = w >> 2;
    int myBh = (w & 3) >> 1;

    const char* aSrc[2][2];
#pragma unroll
    for (int h = 0; h < 2; ++h)
#pragma unroll
        for (int gi = 0; gi < 2; ++gi) {
            int row = base + m0 + h * 128 + w * 16 + gi * 8 + (lane >> 3);
            aSrc[h][gi] = reinterpret_cast<const char*>(Abase)
                + (size_t)row * ((size_t)aStrideElems * 2)
                + (unsigned)((((lane & 7) ^ (lane >> 3)) * 16));
        }
    const char* bSrc[2];
#pragma unroll
    for (int h = 0; h < 2; ++h)
        bSrc[h] = reinterpret_cast<const char*>(slabs)
            + (size_t)((e * slabsPerE + 2 * nb + h) * KTn) * SLAB
            + w * 2048 + lane * 16;

    unsigned afOff[4], bfOff[2];
#pragma unroll
    for (int a = 0; a < 4; ++a) {
        int rl = a * 16 + (lane & 15);
        afOff[a] = (unsigned)(rl * 128 + (((lane >> 4) ^ (rl & 7)) * 16));
    }
#pragma unroll
    for (int j = 0; j < 2; ++j) {
        int cl = ((w & 3) & 1) * 64 + j * 16 + (lane & 15);
        bfOff[j] = (unsigned)(cl * 128 + (((lane >> 4) ^ (cl & 7)) * 16));
    }

    f32x4 acc[8][4];
#pragma unroll
    for (int a = 0; a < 8; ++a)
#pragma unroll
        for (int j = 0; j < 4; ++j) acc[a][j] = (f32x4){0.f, 0.f, 0.f, 0.f};

    bf16x8 af[8], bfA[4], bfB[4];

    // ---- prologue: issue t0 + t1 fully (16 loads); wait t0 (8 left in flight) ----
    ISS_B(0, 0, 0); ISS_B(0, 1, 0); ISS_A(0, 0, 0); ISS_A(0, 1, 0);
    ISS_B(1, 0, 1); ISS_B(1, 1, 1); ISS_A(1, 0, 1); ISS_A(1, 1, 1);
    VMW8;
    __builtin_amdgcn_s_barrier();
    __builtin_amdgcn_sched_barrier(0);

    int NI = KTn / 2;
#pragma unroll 1
    for (int i = 0; i < NI - 1; ++i) {
        int t2 = 2 * i + 2, t3 = 2 * i + 3;
        // p1: tile 2i quadrant (0,0)
        RD_AF(0, 0); RD_BF(0, 0, bfA);
        PH_SYNC; DO_MFMA(0, 0, bfA); PH_END;
        // p2: (0,1)
        RD_BF(0, 1, bfB);
        PH_SYNC; DO_MFMA(0, 1, bfB); PH_END;
        // p3: (1,0); B[0] halves free -> issue both B halves of t+2
        RD_AF(0, 1); ISS_B(0, 0, t2); ISS_B(0, 1, t2);
        PH_SYNC; DO_MFMA(1, 0, bfA); PH_END;
        // p4: (1,1); A[0] halves free -> issue both A halves of t+2; wait t+1
        ISS_A(0, 0, t2); ISS_A(0, 1, t2);
        VMW8; PH_SYNC; DO_MFMA(1, 1, bfB); PH_END;
        // p5: tile 2i+1 quadrant (0,0)
        RD_AF(1, 0); RD_BF(1, 0, bfA);
        PH_SYNC; DO_MFMA(0, 0, bfA); PH_END;
        // p6: (0,1)
        RD_BF(1, 1, bfB);
        PH_SYNC; DO_MFMA(0, 1, bfB); PH_END;
        // p7: (1,0); issue both B halves of t+3
        RD_AF(1, 1); ISS_B(1, 0, t3); ISS_B(1, 1, t3);
        PH_SYNC; DO_MFMA(1, 0, bfA); PH_END;
        // p8: (1,1); issue both A halves of t+3; wait t+2
        ISS_A(1, 0, t3); ISS_A(1, 1, t3);
        VMW8; PH_SYNC; DO_MFMA(1, 1, bfB); PH_END;
    }
    {   // ---- peeled final group (tiles KTn-2, KTn-1), no issues ----
        RD_AF(0, 0); RD_BF(0, 0, bfA);
        PH_SYNC; DO_MFMA(0, 0, bfA); PH_END;
        RD_BF(0, 1, bfB);
        PH_SYNC; DO_MFMA(0, 1, bfB); PH_END;
        RD_AF(0, 1);
        PH_SYNC; DO_MFMA(1, 0, bfA); PH_END;
        VMW0; PH_SYNC; DO_MFMA(1, 1, bfB); PH_END;
        RD_AF(1, 0); RD_BF(1, 0, bfA);
        PH_SYNC; DO_MFMA(0, 0, bfA); PH_END;
        RD_BF(1, 1, bfB);
        PH_SYNC; DO_MFMA(0, 1, bfB); PH_END;
        RD_AF(1, 1);
        PH_SYNC; DO_MFMA(1, 0, bfA); PH_END;
        PH_SYNC; DO_MFMA(1, 1, bfB); PH_END;
    }

    // ---- epilogue ----
    int hi = lane >> 4, lo = lane & 15;
    int wrow = (w >> 2) * 128, wcol = (w & 3) * 64;
#pragma unroll
    for (int ai = 0; ai < 8; ++ai) {
#pragma unroll
        for (int q = 0; q < 4; ++q) {
            int rowL = wrow + ai * 16 + hi * 4 + q;
            if (rowL < rows) {
                int pr = base + m0 + rowL;
                if constexpr (MODE == 0) {
                    short* dst = outS + (size_t)pr * Fc + nb * 256;
#pragma unroll
                    for (int ji = 0; ji < 4; ++ji) {
                        float z = acc[ai][ji][q];
                        dst[wcol + ji * 16 + lo] = f2bfs(z / (1.f + __expf(-z)));
                    }
                } else if constexpr (MODE == 1) {
                    size_t off = (size_t)pr * Fc + nb * 256;
                    const short* s1 = hA + off;
                    short* dst = outS + off;
#pragma unroll
                    for (int ji = 0; ji < 4; ++ji) {
                        int c = wcol + ji * 16 + lo;
                        dst[c] = f2bfs(bf2f(s1[c]) * acc[ai][ji][q]);
                    }
                } else {
                    int tok = pairTok[pr];
                    float wt = pairW[pr];
                    float* dst = outF + (size_t)tok * HID + nb * 256;
#pragma unroll
                    for (int ji = 0; ji < 4; ++ji)
                        atomicAdd(dst + wcol + ji * 16 + lo, acc[ai][ji][q] * wt);
                }
            }
        }
    }
}

// ---------------- host ----------------
extern "C" void kernel_launch(void* const* d_in, const int* in_sizes, int n_in,
                              void* d_out, int out_size, void* d_ws, size_t ws_size,
                              hipStream_t stream)
{
    const float* x   = (const float*)d_in[0];
    const float* gw  = (const float*)d_in[1];
    const float* w1s = (const float*)d_in[2];
    const float* w3s = (const float*)d_in[3];
    const float* w2s = (const float*)d_in[4];
    float* out = (float*)d_out;
    char* ws = (char*)d_ws;

    int*   counts  = (int*)(ws + 0);
    int*   bases   = (int*)(ws + 128);
    int*   sel0    = (int*)(ws + 1024);
    int*   sel1    = (int*)(ws + 1024 + 4 * T_TOK);
    float* w0f     = (float*)(ws + 1024 + 8 * T_TOK);
    float* w1f     = (float*)(ws + 1024 + 12 * T_TOK);
    int*   pairTok = (int*)(ws + 1024 + 16 * T_TOK);
    float* pairW   = (float*)(ws + 1024 + 16 * T_TOK + 4 * NPAIR);

    // NC must keep FFN chunk a multiple of 256 (28/NC integral)
    const int cands[6] = {1, 2, 4, 7, 14, 28};
    int NC = 28;
    for (int ci = 0; ci < 6; ++ci) {
        int nc = cands[ci];
        int NB128 = 56 / nc, Fcc = FFN / nc, KT2c = Fcc / 64;
        size_t sz13 = (size_t)NEXP * NB128 * KT1 * SLAB;
        size_t sz2  = (size_t)NEXP * 16 * KT2c * SLAB;
        size_t sxp  = (size_t)(NPAIR + 256) * HID * 2;
        size_t shb  = (size_t)(NPAIR + 256) * Fcc * 2;
        if (262144 + 2 * sz13 + sz2 + sxp + 2 * shb <= ws_size) { NC = nc; break; }
    }
    int NB128 = 56 / NC, NB256 = 28 / NC, Fc = FFN / NC, KT2c = Fc / 64;
    size_t sz13 = (size_t)NEXP * NB128 * KT1 * SLAB;
    size_t sz2  = (size_t)NEXP * 16 * KT2c * SLAB;
    size_t sxp  = (size_t)(NPAIR + 256) * HID * 2;
    size_t shb  = (size_t)(NPAIR + 256) * Fc * 2;
    short* w1r   = (short*)(ws + 262144);
    short* w3r   = (short*)(ws + 262144 + sz13);
    short* w2r   = (short*)(ws + 262144 + 2 * sz13);
    short* xperm = (short*)(ws + 262144 + 2 * sz13 + sz2);
    short* hAb   = (short*)(ws + 262144 + 2 * sz13 + sz2 + sxp);
    short* hbuf  = (short*)(ws + 262144 + 2 * sz13 + sz2 + sxp + shb);

    hipMemsetAsync(ws, 0, 1024, stream);
    hipMemsetAsync(d_out, 0, (size_t)out_size * sizeof(float), stream);
    moe_router<<<T_TOK / 4, 256, 0, stream>>>(x, gw, counts, sel0, sel1, w0f, w1f);
    moe_bases<<<1, 64, 0, stream>>>(counts, bases);
    moe_scatter<<<NEXP, 256, 0, stream>>>(sel0, sel1, w0f, w1f, bases, pairTok, pairW);
    moe_xperm<<<NPAIR / 4, 256, 0, stream>>>(x, pairTok, xperm);

    int grid1 = NEXP * NB256 * MT_G;
    int grid2 = NEXP * 8 * MT_G;
    for (int c = 0; c < NC; ++c) {
        moe_retile<<<NEXP * NB128 * KT1, 256, 0, stream>>>(
            w1s + (size_t)c * Fc, (size_t)HID * FFN, FFN, w1r, NB128, KT1);
        moe_retile<<<NEXP * NB128 * KT1, 256, 0, stream>>>(
            w3s + (size_t)c * Fc, (size_t)HID * FFN, FFN, w3r, NB128, KT1);
        moe_retile<<<NEXP * 16 * KT2c, 256, 0, stream>>>(
            w2s + (size_t)(c * Fc) * HID, (size_t)FFN * HID, HID, w2r, 16, KT2c);
        moe_gemm256<0><<<grid1, 512, 0, stream>>>(
            xperm, HID, w1r, NB128, KT1, NB256, counts, bases,
            nullptr, hAb, nullptr, nullptr, nullptr, Fc);
        moe_gemm256<1><<<grid1, 512, 0, stream>>>(
            xperm, HID, w3r, NB128, KT1, NB256, counts, bases,
            hAb, hbuf, nullptr, nullptr, nullptr, Fc);
        moe_gemm256<2><<<grid2, 512, 0, stream>>>(
            hbuf, Fc, w2r, 16, KT2c, 8, counts, bases,
            nullptr, nullptr, pairTok, pairW, out, Fc);
    }
    (void)in_sizes; (void)n_in;
}